// Round 10
// baseline (137.562 us; speedup 1.0000x reference)
//
#include <hip/hip_runtime.h>
#include <hip/hip_bf16.h>
#include <math.h>

#define Bn   4
#define CIN  128
#define Hh   64
#define Ww   64
#define HW   4096
#define CMID 64
#define KOC  100      // (scale*k_up)^2
#define H2   128
#define W2d  128
#define HW2  16384
#define KUP  5
#define BN_EPS 1e-5f

typedef __attribute__((ext_vector_type(8)))  short  short8v;
typedef __attribute__((ext_vector_type(16))) float  float16v;

__device__ __forceinline__ ushort f2bf(float v) {
    __hip_bfloat16 h = __float2bfloat16(v);
    return *(ushort*)&h;
}

// ---------------- Kernel A: 1x1 conv + BN + SiLU -> W1b NHWC bf16 [b][pix][64]
// thread = 4 px (float4) x 2 co. Piggyback: first 288 blocks build
// Abf[tap][kop 128][cm 64] bf16 (ko padded with 0).
__global__ __launch_bounds__(256) void comp_kernel(
    const float* __restrict__ X,
    const float* __restrict__ cw,
    const float* __restrict__ cg,
    const float* __restrict__ cb,
    const float* __restrict__ ew,
    unsigned* __restrict__ W1b,     // [b][pix][32] packed bf16 pairs
    ushort* __restrict__ Abf)       // [9][128][64]
{
    int tid = threadIdx.x;
    if (blockIdx.x < 288) {         // A-prep: 288*256 = 73728 = 9*128*64
        int i   = blockIdx.x * 256 + tid;
        int cm  = i & 63;
        int kop = (i >> 6) & 127;
        int tap = i >> 13;
        float v = (kop < KOC) ? ew[((size_t)(kop * CMID + cm)) * 9 + tap] : 0.f;
        Abf[i] = f2bf(v);
    }

    int gt  = blockIdx.x * 256 + tid;   // 512 blocks = 131072 threads
    int pg  = gt & 1023;                // 1024 pixel-quads per b
    int cog = (gt >> 10) & 31;          // 32 groups of 2 co (block-uniform)
    int b   = gt >> 15;
    int pix = pg * 4;
    int co0 = cog * 2;

    const float* xb = X + (size_t)b * CIN * HW + pix;
    float4 acc0 = make_float4(0.f, 0.f, 0.f, 0.f);
    float4 acc1 = make_float4(0.f, 0.f, 0.f, 0.f);

#pragma unroll 4
    for (int ci = 0; ci < CIN; ++ci) {
        float4 xv = *(const float4*)(xb + (size_t)ci * HW);
        float w0 = cw[(size_t)co0 * CIN + ci];
        float w1 = cw[(size_t)(co0 + 1) * CIN + ci];
        acc0.x += xv.x * w0; acc0.y += xv.y * w0; acc0.z += xv.z * w0; acc0.w += xv.w * w0;
        acc1.x += xv.x * w1; acc1.y += xv.y * w1; acc1.z += xv.z * w1; acc1.w += xv.w * w1;
    }

    float inv_s = rsqrtf(1.0f + BN_EPS);
    float s0 = cg[co0] * inv_s,     bb0 = cb[co0];
    float s1 = cg[co0 + 1] * inv_s, bb1 = cb[co0 + 1];
    float r0[4] = {acc0.x, acc0.y, acc0.z, acc0.w};
    float r1[4] = {acc1.x, acc1.y, acc1.z, acc1.w};
#pragma unroll
    for (int i = 0; i < 4; ++i) {
        float v0 = r0[i] * s0 + bb0; v0 = v0 / (1.f + expf(-v0));
        float v1 = r1[i] * s1 + bb1; v1 = v1 / (1.f + expf(-v1));
        unsigned pk = (unsigned)f2bf(v0) | ((unsigned)f2bf(v1) << 16);
        W1b[((size_t)b * HW + pix + i) * 32 + cog] = pk;
    }
}

// ---------------- Kernel B: 3x3 conv (implicit GEMM, MFMA bf16) + BN + softmax
// block = (b, h, w-half). MFMA phase as R8; then acc -> LDS [128 ko][32 px],
// then 128 threads do BN + pixel-shuffle softmax and write Wsm planes.
__global__ __launch_bounds__(256) void enc_kernel(
    const ushort* __restrict__ W1b_us,   // [b][pix][64] bf16
    const ushort* __restrict__ Abf,      // [9][128][64] bf16
    const float* __restrict__ eg,
    const float* __restrict__ eb,
    float* __restrict__ Wsm)             // [b][100][4096] softmax weights
{
    __shared__ float lsm[128 * 32];      // 16 KB; first 14688 B aliased as B tile
    ushort* Bs = (ushort*)lsm;           // [3 rows][34 w][cm pad 72]

    int bid   = blockIdx.x;              // b*128 + h*2 + whalf -> 512 blocks
    int whalf = bid & 1;
    int h     = (bid >> 1) & 63;
    int b     = bid >> 7;
    int w0    = whalf * 32;
    int tid   = threadIdx.x;

    // stage B tile (bf16-pair granularity, coalesced in cm)
    const unsigned* src  = (const unsigned*)W1b_us;  // [b][pix][32]
    unsigned*       dstu = (unsigned*)Bs;            // w-slot stride 36 uints
    for (int i = tid; i < 3 * 34 * 32; i += 256) {
        int cp = i & 31;
        int t  = i >> 5;
        int wl = t % 34;
        int r  = t / 34;
        int gr = h - 1 + r, gw = w0 - 1 + wl;
        unsigned val = 0u;
        if ((unsigned)gr < 64u && (unsigned)gw < 64u)
            val = src[((size_t)b * HW + gr * 64 + gw) * 32 + cp];
        dstu[(r * 34 + wl) * 36 + cp] = val;
    }
    __syncthreads();

    int lane = tid & 63;
    int wid  = tid >> 6;                 // M-tile: ko base = wid*32
    int n    = lane & 31;
    int q    = lane >> 5;                // 0/1 -> k half

    float16v acc;
#pragma unroll
    for (int i = 0; i < 16; ++i) acc[i] = 0.f;

    const ushort* Arow = Abf + ((size_t)(wid * 32 + n)) * 64 + q * 8;

#pragma unroll
    for (int tap = 0; tap < 9; ++tap) {
        int dy = tap / 3, dx = tap % 3;
        int bbase = ((dy * 34) + n + dx) * 72 + q * 8;     // ushort idx, 16B aligned
        const ushort* Atap = Arow + (size_t)tap * 128 * 64;
#pragma unroll
        for (int c = 0; c < 4; ++c) {
            short8v a = *(const short8v*)(Atap + c * 16);
            short8v bf = *(const short8v*)(Bs + bbase + c * 16);
            acc = __builtin_amdgcn_mfma_f32_32x32x16_bf16(a, bf, acc, 0, 0, 0);
        }
    }

    __syncthreads();                     // all waves done reading Bs

    // acc -> lsm: col = n (pixel), row = (reg&3)+8*(reg>>2)+4*q (ko offset)
#pragma unroll
    for (int reg = 0; reg < 16; ++reg) {
        int row = (reg & 3) + 8 * (reg >> 2) + 4 * q;
        lsm[(wid * 32 + row) * 32 + n] = acc[reg];
    }
    __syncthreads();

    // BN + softmax over 25 taps; thread = (px, sub), 128 threads
    if (tid < 128) {
        int px  = tid & 31;
        int sub = tid >> 5;
        float inv_s = rsqrtf(1.0f + BN_EPS);
        float v[25];
        float m = -1e30f;
#pragma unroll
        for (int k = 0; k < 25; ++k) {
            int ko = 4 * k + sub;
            v[k] = lsm[ko * 32 + px] * (eg[ko] * inv_s) + eb[ko];
            m = fmaxf(m, v[k]);
        }
        float sum = 0.f;
#pragma unroll
        for (int k = 0; k < 25; ++k) {
            v[k] = expf(v[k] - m);
            sum += v[k];
        }
        float inv = 1.f / sum;
        float* po = Wsm + (size_t)b * KOC * HW + h * 64 + w0 + px;
#pragma unroll
        for (int k = 0; k < 25; ++k)
            po[(size_t)(4 * k + sub) * HW] = v[k] * inv;
    }
}

// ---------------- Kernel C: CARAFE reassembly
// block = (b, h, 32-px half-row). Cooperative coalesced stage of the block's
// 100x32 weights from Wsm planes into LDS (all 256 threads), then
// 32 px x 8 channel-groups; each thread caches its px's 100 weights in VGPRs,
// loops 16 channels: 25 coalesced X loads -> 4 outputs (100 FMA).
// (parity fold: floor((h2-4+2*ki)/2) = h + ki - 2 for both parities of h2)
__global__ __launch_bounds__(256) void carafe_kernel(
    const float* __restrict__ X,
    const float* __restrict__ Wsm,
    float* __restrict__ out)
{
    __shared__ float wsm[4][25][32];     // 12.8 KB

    int bid   = blockIdx.x;              // b*128 + h*2 + whalf -> 512 blocks
    int whalf = bid & 1;
    int h     = (bid >> 1) & 63;
    int b     = bid >> 7;
    int w0    = whalf * 32;
    int tid   = threadIdx.x;

    const float* wsrc = Wsm + (size_t)b * KOC * HW + h * 64 + w0;
    for (int i = tid; i < 3200; i += 256) {      // 100 ko x 32 px
        int px = i & 31;
        int ko = i >> 5;
        wsm[ko & 3][ko >> 2][px] = wsrc[(size_t)ko * HW + px];
    }
    __syncthreads();

    int px  = tid & 31;
    int grp = tid >> 5;                  // 8 groups of 16 channels
    int w   = w0 + px;
    int c0  = grp * 16;

    float wt[100];
#pragma unroll
    for (int sub = 0; sub < 4; ++sub)
#pragma unroll
        for (int k = 0; k < 25; ++k)
            wt[sub * 25 + k] = wsm[sub][k][px];

    int off[25];
#pragma unroll
    for (int ki = 0; ki < 5; ++ki) {
#pragma unroll
        for (int kj = 0; kj < 5; ++kj) {
            int k = ki * 5 + kj;
            int r = h + ki - 2, cc = w + kj - 2;
            bool valid = ((unsigned)r < 64u) && ((unsigned)cc < 64u);
            int rc = r < 0 ? 0 : (r > 63 ? 63 : r);
            int cx = cc < 0 ? 0 : (cc > 63 ? 63 : cc);
            off[k] = rc * Ww + cx;
            if (!valid) { wt[k] = 0.f; wt[25+k] = 0.f; wt[50+k] = 0.f; wt[75+k] = 0.f; }
        }
    }

    const float* xp = X + ((size_t)b * CIN + c0) * HW;
    float* o0 = out + ((size_t)b * CIN + c0) * HW2 + (2 * h) * W2d + 2 * w;

    for (int c = 0; c < 16; ++c) {
        float x[25];
#pragma unroll
        for (int k = 0; k < 25; ++k) x[k] = xp[off[k]];
        float a0 = 0.f, a1 = 0.f, a2 = 0.f, a3 = 0.f;
#pragma unroll
        for (int k = 0; k < 25; ++k) {
            float xv = x[k];
            a0 += wt[k]      * xv;
            a1 += wt[25 + k] * xv;
            a2 += wt[50 + k] * xv;
            a3 += wt[75 + k] * xv;
        }
        *(float2*)o0          = make_float2(a0, a1);
        *(float2*)(o0 + W2d)  = make_float2(a2, a3);
        xp += HW;
        o0 += HW2;
    }
}

extern "C" void kernel_launch(void* const* d_in, const int* in_sizes, int n_in,
                              void* d_out, int out_size, void* d_ws, size_t ws_size,
                              hipStream_t stream)
{
    const float* X  = (const float*)d_in[0];
    const float* cw = (const float*)d_in[1];
    const float* cg = (const float*)d_in[2];
    const float* cb = (const float*)d_in[3];
    const float* ew = (const float*)d_in[4];
    const float* eg = (const float*)d_in[5];
    const float* eb = (const float*)d_in[6];
    float* out = (float*)d_out;

    char* ws = (char*)d_ws;
    unsigned* W1b = (unsigned*)ws;                        // 4*4096*32 u32 = 2 MB
    ushort*   Abf = (ushort*)(ws + 2097152);              // 9*128*64 = 147456 B
    float*    Wsm = (float*)(ws + 2097152 + 147456);      // 6.55 MB

    comp_kernel  <<<512, 256, 0, stream>>>(X, cw, cg, cb, ew, W1b, Abf);
    enc_kernel   <<<512, 256, 0, stream>>>((const ushort*)W1b, Abf, eg, eb, Wsm);
    carafe_kernel<<<512, 256, 0, stream>>>(X, Wsm, out);
}

// Round 11
// 135.474 us; speedup vs baseline: 1.0154x; 1.0154x over previous
//
#include <hip/hip_runtime.h>
#include <hip/hip_bf16.h>
#include <math.h>

#define Bn   4
#define CIN  128
#define Hh   64
#define Ww   64
#define HW   4096
#define CMID 64
#define KOC  100      // (scale*k_up)^2
#define H2   128
#define W2d  128
#define HW2  16384
#define KUP  5
#define BN_EPS 1e-5f

typedef __attribute__((ext_vector_type(8)))  short  short8v;
typedef __attribute__((ext_vector_type(16))) float  float16v;

__device__ __forceinline__ ushort f2bf(float v) {
    __hip_bfloat16 h = __float2bfloat16(v);
    return *(ushort*)&h;
}

// ---------------- Kernel A: 1x1 conv + BN + SiLU -> W1b NHWC bf16 [b][pix][64]
// thread = 4 px (float4) x 2 co. Piggyback: first 288 blocks build
// Abf[tap][kop 128][cm 64] bf16 (ko padded with 0).
__global__ __launch_bounds__(256) void comp_kernel(
    const float* __restrict__ X,
    const float* __restrict__ cw,
    const float* __restrict__ cg,
    const float* __restrict__ cb,
    const float* __restrict__ ew,
    unsigned* __restrict__ W1b,     // [b][pix][32] packed bf16 pairs
    ushort* __restrict__ Abf)       // [9][128][64]
{
    int tid = threadIdx.x;
    if (blockIdx.x < 288) {         // A-prep: 288*256 = 73728 = 9*128*64
        int i   = blockIdx.x * 256 + tid;
        int cm  = i & 63;
        int kop = (i >> 6) & 127;
        int tap = i >> 13;
        float v = (kop < KOC) ? ew[((size_t)(kop * CMID + cm)) * 9 + tap] : 0.f;
        Abf[i] = f2bf(v);
    }

    int gt  = blockIdx.x * 256 + tid;   // 512 blocks = 131072 threads
    int pg  = gt & 1023;                // 1024 pixel-quads per b
    int cog = (gt >> 10) & 31;          // 32 groups of 2 co (block-uniform)
    int b   = gt >> 15;
    int pix = pg * 4;
    int co0 = cog * 2;

    const float* xb = X + (size_t)b * CIN * HW + pix;
    float4 acc0 = make_float4(0.f, 0.f, 0.f, 0.f);
    float4 acc1 = make_float4(0.f, 0.f, 0.f, 0.f);

#pragma unroll 4
    for (int ci = 0; ci < CIN; ++ci) {
        float4 xv = *(const float4*)(xb + (size_t)ci * HW);
        float w0 = cw[(size_t)co0 * CIN + ci];
        float w1 = cw[(size_t)(co0 + 1) * CIN + ci];
        acc0.x += xv.x * w0; acc0.y += xv.y * w0; acc0.z += xv.z * w0; acc0.w += xv.w * w0;
        acc1.x += xv.x * w1; acc1.y += xv.y * w1; acc1.z += xv.z * w1; acc1.w += xv.w * w1;
    }

    float inv_s = rsqrtf(1.0f + BN_EPS);
    float s0 = cg[co0] * inv_s,     bb0 = cb[co0];
    float s1 = cg[co0 + 1] * inv_s, bb1 = cb[co0 + 1];
    float r0[4] = {acc0.x, acc0.y, acc0.z, acc0.w};
    float r1[4] = {acc1.x, acc1.y, acc1.z, acc1.w};
#pragma unroll
    for (int i = 0; i < 4; ++i) {
        float v0 = r0[i] * s0 + bb0; v0 = v0 / (1.f + expf(-v0));
        float v1 = r1[i] * s1 + bb1; v1 = v1 / (1.f + expf(-v1));
        unsigned pk = (unsigned)f2bf(v0) | ((unsigned)f2bf(v1) << 16);
        W1b[((size_t)b * HW + pix + i) * 32 + cog] = pk;
    }
}

// ---------------- Kernel B: fused 3x3-conv(MFMA) + BN + softmax + CARAFE
// block = (b, h, whalf): 32 pixels. Phases:
//  1. stage shifted W1 tile [3][34][cm pad 72] bf16 in LDS
//  2. implicit-GEMM: C[128 ko][32 px] via 36 MFMA/wave, acc in AGPRs
//  3. acc -> lsm[128 ko][32 px] (fp32, aliases the B tile)
//  4. 128 threads: BN + pixel-shuffle softmax over 25 taps, IN-PLACE in lsm
//  5. carafe: 32 px x 8 grp x 16 ch; wt[100] from LDS, 25 coalesced X loads
//     -> 4 outputs per channel (parity fold: src row = h+ki-2 for both pars)
__global__ __launch_bounds__(256) void fused_kernel(
    const float* __restrict__ X,
    const ushort* __restrict__ W1b_us,   // [b][pix][64] bf16
    const ushort* __restrict__ Abf,      // [9][128][64] bf16
    const float* __restrict__ eg,
    const float* __restrict__ eb,
    float* __restrict__ out)
{
    __shared__ float lsm[128 * 32];      // 16 KB; first 14688 B aliased as B tile
    ushort* Bs = (ushort*)lsm;           // [3 rows][34 w][cm pad 72]

    int bid   = blockIdx.x;              // b*128 + h*2 + whalf -> 512 blocks
    int whalf = bid & 1;
    int h     = (bid >> 1) & 63;
    int b     = bid >> 7;
    int w0    = whalf * 32;
    int tid   = threadIdx.x;

    // ---- phase 1: stage B tile (bf16-pair granularity, coalesced in cm)
    const unsigned* src  = (const unsigned*)W1b_us;  // [b][pix][32]
    unsigned*       dstu = (unsigned*)Bs;            // w-slot stride 36 uints
    for (int i = tid; i < 3 * 34 * 32; i += 256) {
        int cp = i & 31;
        int t  = i >> 5;
        int wl = t % 34;
        int r  = t / 34;
        int gr = h - 1 + r, gw = w0 - 1 + wl;
        unsigned val = 0u;
        if ((unsigned)gr < 64u && (unsigned)gw < 64u)
            val = src[((size_t)b * HW + gr * 64 + gw) * 32 + cp];
        dstu[(r * 34 + wl) * 36 + cp] = val;
    }
    __syncthreads();

    // ---- phase 2: MFMA
    int lane = tid & 63;
    int wid  = tid >> 6;                 // M-tile: ko base = wid*32
    int n    = lane & 31;
    int q    = lane >> 5;                // 0/1 -> k half

    float16v acc;
#pragma unroll
    for (int i = 0; i < 16; ++i) acc[i] = 0.f;

    const ushort* Arow = Abf + ((size_t)(wid * 32 + n)) * 64 + q * 8;

#pragma unroll
    for (int tap = 0; tap < 9; ++tap) {
        int dy = tap / 3, dx = tap % 3;
        int bbase = ((dy * 34) + n + dx) * 72 + q * 8;     // ushort idx, 16B aligned
        const ushort* Atap = Arow + (size_t)tap * 128 * 64;
#pragma unroll
        for (int c = 0; c < 4; ++c) {
            short8v a  = *(const short8v*)(Atap + c * 16);
            short8v bf = *(const short8v*)(Bs + bbase + c * 16);
            acc = __builtin_amdgcn_mfma_f32_32x32x16_bf16(a, bf, acc, 0, 0, 0);
        }
    }
    __syncthreads();                     // all waves done reading Bs

    // ---- phase 3: acc -> lsm (col = n, row = (reg&3)+8*(reg>>2)+4*q)
#pragma unroll
    for (int reg = 0; reg < 16; ++reg) {
        int row = (reg & 3) + 8 * (reg >> 2) + 4 * q;
        lsm[(wid * 32 + row) * 32 + n] = acc[reg];
    }
    __syncthreads();

    // ---- phase 4: BN + softmax over 25 taps, in-place (thread = px,sub)
    if (tid < 128) {
        int px  = tid & 31;
        int sub = tid >> 5;
        float inv_s = rsqrtf(1.0f + BN_EPS);
        float v[25];
        float m = -1e30f;
#pragma unroll
        for (int k = 0; k < 25; ++k) {
            int ko = 4 * k + sub;
            v[k] = lsm[ko * 32 + px] * (eg[ko] * inv_s) + eb[ko];
            m = fmaxf(m, v[k]);
        }
        float sum = 0.f;
#pragma unroll
        for (int k = 0; k < 25; ++k) {
            v[k] = expf(v[k] - m);
            sum += v[k];
        }
        float inv = 1.f / sum;
#pragma unroll
        for (int k = 0; k < 25; ++k)
            lsm[(4 * k + sub) * 32 + px] = v[k] * inv;
    }
    __syncthreads();

    // ---- phase 5: CARAFE reassembly
    int px  = tid & 31;
    int grp = tid >> 5;                  // 8 groups of 16 channels
    int w   = w0 + px;
    int c0  = grp * 16;

    float wt[100];
#pragma unroll
    for (int sub = 0; sub < 4; ++sub)
#pragma unroll
        for (int k = 0; k < 25; ++k)
            wt[sub * 25 + k] = lsm[(4 * k + sub) * 32 + px];

    int off[25];
#pragma unroll
    for (int ki = 0; ki < 5; ++ki) {
#pragma unroll
        for (int kj = 0; kj < 5; ++kj) {
            int k = ki * 5 + kj;
            int r = h + ki - 2, cc = w + kj - 2;
            bool valid = ((unsigned)r < 64u) && ((unsigned)cc < 64u);
            int rc = r < 0 ? 0 : (r > 63 ? 63 : r);
            int cx = cc < 0 ? 0 : (cc > 63 ? 63 : cc);
            off[k] = rc * Ww + cx;
            if (!valid) { wt[k] = 0.f; wt[25+k] = 0.f; wt[50+k] = 0.f; wt[75+k] = 0.f; }
        }
    }

    const float* xp = X + ((size_t)b * CIN + c0) * HW;
    float* o0 = out + ((size_t)b * CIN + c0) * HW2 + (2 * h) * W2d + 2 * w;

    for (int c = 0; c < 16; ++c) {
        float x[25];
#pragma unroll
        for (int k = 0; k < 25; ++k) x[k] = xp[off[k]];
        float a0 = 0.f, a1 = 0.f, a2 = 0.f, a3 = 0.f;
#pragma unroll
        for (int k = 0; k < 25; ++k) {
            float xv = x[k];
            a0 += wt[k]      * xv;
            a1 += wt[25 + k] * xv;
            a2 += wt[50 + k] * xv;
            a3 += wt[75 + k] * xv;
        }
        *(float2*)o0          = make_float2(a0, a1);
        *(float2*)(o0 + W2d)  = make_float2(a2, a3);
        xp += HW;
        o0 += HW2;
    }
}

extern "C" void kernel_launch(void* const* d_in, const int* in_sizes, int n_in,
                              void* d_out, int out_size, void* d_ws, size_t ws_size,
                              hipStream_t stream)
{
    const float* X  = (const float*)d_in[0];
    const float* cw = (const float*)d_in[1];
    const float* cg = (const float*)d_in[2];
    const float* cb = (const float*)d_in[3];
    const float* ew = (const float*)d_in[4];
    const float* eg = (const float*)d_in[5];
    const float* eb = (const float*)d_in[6];
    float* out = (float*)d_out;

    char* ws = (char*)d_ws;
    unsigned* W1b = (unsigned*)ws;                        // 4*4096*32 u32 = 2 MB
    ushort*   Abf = (ushort*)(ws + 2097152);              // 9*128*64 = 147456 B

    comp_kernel <<<512, 256, 0, stream>>>(X, cw, cg, cb, ew, W1b, Abf);
    fused_kernel<<<512, 256, 0, stream>>>(X, (const ushort*)W1b, Abf, eg, eb, out);
}

// Round 12
// 129.299 us; speedup vs baseline: 1.0639x; 1.0478x over previous
//
#include <hip/hip_runtime.h>
#include <hip/hip_bf16.h>
#include <math.h>

#define Bn   4
#define CIN  128
#define Hh   64
#define Ww   64
#define HW   4096
#define CMID 64
#define KOC  100      // (scale*k_up)^2
#define H2   128
#define W2d  128
#define HW2  16384
#define KUP  5
#define BN_EPS 1e-5f

typedef __attribute__((ext_vector_type(8)))  short  short8v;
typedef __attribute__((ext_vector_type(16))) float  float16v;

__device__ __forceinline__ ushort f2bf(float v) {
    __hip_bfloat16 h = __float2bfloat16(v);
    return *(ushort*)&h;
}

// ---------------- Kernel A: 1x1 conv + BN + SiLU -> W1b NHWC bf16 [b][pix][64]
// thread = 4 px (float4) x 2 co. Piggyback: first 288 blocks build
// Abf[tap][kop 128][cm 64] bf16 (ko padded with 0).
__global__ __launch_bounds__(256) void comp_kernel(
    const float* __restrict__ X,
    const float* __restrict__ cw,
    const float* __restrict__ cg,
    const float* __restrict__ cb,
    const float* __restrict__ ew,
    unsigned* __restrict__ W1b,     // [b][pix][32] packed bf16 pairs
    ushort* __restrict__ Abf)       // [9][128][64]
{
    int tid = threadIdx.x;
    if (blockIdx.x < 288) {         // A-prep: 288*256 = 73728 = 9*128*64
        int i   = blockIdx.x * 256 + tid;
        int cm  = i & 63;
        int kop = (i >> 6) & 127;
        int tap = i >> 13;
        float v = (kop < KOC) ? ew[((size_t)(kop * CMID + cm)) * 9 + tap] : 0.f;
        Abf[i] = f2bf(v);
    }

    int gt  = blockIdx.x * 256 + tid;   // 512 blocks = 131072 threads
    int pg  = gt & 1023;                // 1024 pixel-quads per b
    int cog = (gt >> 10) & 31;          // 32 groups of 2 co (block-uniform)
    int b   = gt >> 15;
    int pix = pg * 4;
    int co0 = cog * 2;

    const float* xb = X + (size_t)b * CIN * HW + pix;
    float4 acc0 = make_float4(0.f, 0.f, 0.f, 0.f);
    float4 acc1 = make_float4(0.f, 0.f, 0.f, 0.f);

#pragma unroll 4
    for (int ci = 0; ci < CIN; ++ci) {
        float4 xv = *(const float4*)(xb + (size_t)ci * HW);
        float w0 = cw[(size_t)co0 * CIN + ci];
        float w1 = cw[(size_t)(co0 + 1) * CIN + ci];
        acc0.x += xv.x * w0; acc0.y += xv.y * w0; acc0.z += xv.z * w0; acc0.w += xv.w * w0;
        acc1.x += xv.x * w1; acc1.y += xv.y * w1; acc1.z += xv.z * w1; acc1.w += xv.w * w1;
    }

    float inv_s = rsqrtf(1.0f + BN_EPS);
    float s0 = cg[co0] * inv_s,     bb0 = cb[co0];
    float s1 = cg[co0 + 1] * inv_s, bb1 = cb[co0 + 1];
    float r0[4] = {acc0.x, acc0.y, acc0.z, acc0.w};
    float r1[4] = {acc1.x, acc1.y, acc1.z, acc1.w};
#pragma unroll
    for (int i = 0; i < 4; ++i) {
        float v0 = r0[i] * s0 + bb0; v0 = v0 / (1.f + expf(-v0));
        float v1 = r1[i] * s1 + bb1; v1 = v1 / (1.f + expf(-v1));
        unsigned pk = (unsigned)f2bf(v0) | ((unsigned)f2bf(v1) << 16);
        W1b[((size_t)b * HW + pix + i) * 32 + cog] = pk;
    }
}

// ---------------- Kernel B: 3x3 conv (implicit GEMM, MFMA bf16) + BN + softmax
// block = (b, h, w-half). MFMA phase; acc -> LDS [128 ko][32 px]; 128 threads
// do BN + pixel-shuffle softmax and write Wsm planes (coalesced).
__global__ __launch_bounds__(256) void enc_kernel(
    const ushort* __restrict__ W1b_us,   // [b][pix][64] bf16
    const ushort* __restrict__ Abf,      // [9][128][64] bf16
    const float* __restrict__ eg,
    const float* __restrict__ eb,
    float* __restrict__ Wsm)             // [b][100][4096] softmax weights
{
    __shared__ float lsm[128 * 32];      // 16 KB; first 14688 B aliased as B tile
    ushort* Bs = (ushort*)lsm;           // [3 rows][34 w][cm pad 72]

    int bid   = blockIdx.x;              // b*128 + h*2 + whalf -> 512 blocks
    int whalf = bid & 1;
    int h     = (bid >> 1) & 63;
    int b     = bid >> 7;
    int w0    = whalf * 32;
    int tid   = threadIdx.x;

    // stage B tile (bf16-pair granularity, coalesced in cm)
    const unsigned* src  = (const unsigned*)W1b_us;  // [b][pix][32]
    unsigned*       dstu = (unsigned*)Bs;            // w-slot stride 36 uints
    for (int i = tid; i < 3 * 34 * 32; i += 256) {
        int cp = i & 31;
        int t  = i >> 5;
        int wl = t % 34;
        int r  = t / 34;
        int gr = h - 1 + r, gw = w0 - 1 + wl;
        unsigned val = 0u;
        if ((unsigned)gr < 64u && (unsigned)gw < 64u)
            val = src[((size_t)b * HW + gr * 64 + gw) * 32 + cp];
        dstu[(r * 34 + wl) * 36 + cp] = val;
    }
    __syncthreads();

    int lane = tid & 63;
    int wid  = tid >> 6;                 // M-tile: ko base = wid*32
    int n    = lane & 31;
    int q    = lane >> 5;                // 0/1 -> k half

    float16v acc;
#pragma unroll
    for (int i = 0; i < 16; ++i) acc[i] = 0.f;

    const ushort* Arow = Abf + ((size_t)(wid * 32 + n)) * 64 + q * 8;

#pragma unroll
    for (int tap = 0; tap < 9; ++tap) {
        int dy = tap / 3, dx = tap % 3;
        int bbase = ((dy * 34) + n + dx) * 72 + q * 8;     // ushort idx, 16B aligned
        const ushort* Atap = Arow + (size_t)tap * 128 * 64;
#pragma unroll
        for (int c = 0; c < 4; ++c) {
            short8v a  = *(const short8v*)(Atap + c * 16);
            short8v bf = *(const short8v*)(Bs + bbase + c * 16);
            acc = __builtin_amdgcn_mfma_f32_32x32x16_bf16(a, bf, acc, 0, 0, 0);
        }
    }
    __syncthreads();                     // all waves done reading Bs

    // acc -> lsm: col = n (pixel), row = (reg&3)+8*(reg>>2)+4*q (ko offset)
#pragma unroll
    for (int reg = 0; reg < 16; ++reg) {
        int row = (reg & 3) + 8 * (reg >> 2) + 4 * q;
        lsm[(wid * 32 + row) * 32 + n] = acc[reg];
    }
    __syncthreads();

    // BN + softmax over 25 taps; thread = (px, sub), 128 threads
    if (tid < 128) {
        int px  = tid & 31;
        int sub = tid >> 5;
        float inv_s = rsqrtf(1.0f + BN_EPS);
        float v[25];
        float m = -1e30f;
#pragma unroll
        for (int k = 0; k < 25; ++k) {
            int ko = 4 * k + sub;
            v[k] = lsm[ko * 32 + px] * (eg[ko] * inv_s) + eb[ko];
            m = fmaxf(m, v[k]);
        }
        float sum = 0.f;
#pragma unroll
        for (int k = 0; k < 25; ++k) {
            v[k] = expf(v[k] - m);
            sum += v[k];
        }
        float inv = 1.f / sum;
        float* po = Wsm + (size_t)b * KOC * HW + h * 64 + w0 + px;
#pragma unroll
        for (int k = 0; k < 25; ++k)
            po[(size_t)(4 * k + sub) * HW] = v[k] * inv;
    }
}

// ---------------- Kernel C: CARAFE reassembly, tap-outer / channel-inner.
// block = (b, h, whalf, ch-half): 1024 blocks. Stage 100x32 weights into LDS
// as wsm2[k][px][4] (one ds_read_b128 per tap). Thread = (px, grp-of-8-ch):
// per tap: 1 b128 LDS read + 4 mask-mul + 8 coalesced X loads -> 32 FMA.
// acc[4][8] = 32 VGPR -> high occupancy; x shared across 4 subs.
// (parity fold: floor((h2-4+2*ki)/2) = h + ki - 2 for both parities of h2)
__global__ __launch_bounds__(256) void carafe_kernel(
    const float* __restrict__ X,
    const float* __restrict__ Wsm,
    float* __restrict__ out)
{
    __shared__ float wsm2[25 * 32 * 4];  // 12.8 KB, [k][px][sub]

    int bid   = blockIdx.x;              // ((b*64 + h)*2 + whalf)*2 + chh
    int chh   = bid & 1;
    int whalf = (bid >> 1) & 1;
    int h     = (bid >> 2) & 63;
    int b     = bid >> 8;
    int w0    = whalf * 32;
    int tid   = threadIdx.x;

    // stage weights from planes (coalesced reads; transpose to [k][px][sub])
    const float* wsrc = Wsm + (size_t)b * KOC * HW + h * 64 + w0;
    for (int i = tid; i < 3200; i += 256) {
        int px_ = i & 31;
        int ko  = i >> 5;                // 0..99
        wsm2[((ko >> 2) * 32 + px_) * 4 + (ko & 3)] = wsrc[(size_t)ko * HW + px_];
    }
    __syncthreads();

    int px  = tid & 31;
    int grp = tid >> 5;                  // 8 groups of 8 channels
    int w   = w0 + px;
    int c0  = chh * 64 + grp * 8;

    float a0[8], a1[8], a2[8], a3[8];
#pragma unroll
    for (int c = 0; c < 8; ++c) { a0[c] = 0.f; a1[c] = 0.f; a2[c] = 0.f; a3[c] = 0.f; }

    const float* xb = X + ((size_t)b * CIN + c0) * HW;

#pragma unroll
    for (int k = 0; k < 25; ++k) {
        int ki = k / 5, kj = k % 5;
        int r = h + ki - 2, cc = w + kj - 2;
        float msk = (((unsigned)r < 64u) && ((unsigned)cc < 64u)) ? 1.f : 0.f;
        int rc = r < 0 ? 0 : (r > 63 ? 63 : r);
        int cx = cc < 0 ? 0 : (cc > 63 ? 63 : cc);
        int off = rc * Ww + cx;

        float4 wt4 = *(const float4*)&wsm2[(k * 32 + px) * 4];
        float w0v = wt4.x * msk, w1v = wt4.y * msk;
        float w2v = wt4.z * msk, w3v = wt4.w * msk;

        float xv[8];
#pragma unroll
        for (int c = 0; c < 8; ++c) xv[c] = xb[(size_t)c * HW + off];
#pragma unroll
        for (int c = 0; c < 8; ++c) {
            a0[c] += w0v * xv[c];
            a1[c] += w1v * xv[c];
            a2[c] += w2v * xv[c];
            a3[c] += w3v * xv[c];
        }
    }

    float* o0 = out + ((size_t)b * CIN + c0) * HW2 + (2 * h) * W2d + 2 * w;
#pragma unroll
    for (int c = 0; c < 8; ++c) {
        *(float2*)o0         = make_float2(a0[c], a1[c]);
        *(float2*)(o0 + W2d) = make_float2(a2[c], a3[c]);
        o0 += HW2;
    }
}

extern "C" void kernel_launch(void* const* d_in, const int* in_sizes, int n_in,
                              void* d_out, int out_size, void* d_ws, size_t ws_size,
                              hipStream_t stream)
{
    const float* X  = (const float*)d_in[0];
    const float* cw = (const float*)d_in[1];
    const float* cg = (const float*)d_in[2];
    const float* cb = (const float*)d_in[3];
    const float* ew = (const float*)d_in[4];
    const float* eg = (const float*)d_in[5];
    const float* eb = (const float*)d_in[6];
    float* out = (float*)d_out;

    char* ws = (char*)d_ws;
    unsigned* W1b = (unsigned*)ws;                        // 4*4096*32 u32 = 2 MB
    ushort*   Abf = (ushort*)(ws + 2097152);              // 9*128*64 = 147456 B
    float*    Wsm = (float*)(ws + 2097152 + 147456);      // 6.55 MB

    comp_kernel  <<<512, 256, 0, stream>>>(X, cw, cg, cb, ew, W1b, Abf);
    enc_kernel   <<<512, 256, 0, stream>>>((const ushort*)W1b, Abf, eg, eb, Wsm);
    carafe_kernel<<<1024, 256, 0, stream>>>(X, Wsm, out);
}